// Round 9
// baseline (321.709 us; speedup 1.0000x reference)
//
#include <hip/hip_runtime.h>
#include <hip/hip_bf16.h>

#define S_  2048
#define B_  2
#define H_  1024
#define NH_ 16
#define D_  64

typedef short s16x8 __attribute__((ext_vector_type(8)));
typedef float f32x4 __attribute__((ext_vector_type(4)));
typedef unsigned short u16;

__device__ __forceinline__ u16 f2bf(float f) {
    __hip_bfloat16 h = __float2bfloat16(f);
    union { __hip_bfloat16 h; u16 u; } c; c.h = h; return c.u;
}

#define GLOAD_LDS16(g, l) __builtin_amdgcn_global_load_lds( \
    (const __attribute__((address_space(1))) void*)(g),     \
    (__attribute__((address_space(3))) void*)(l), 16, 0, 0)

// ---------------------------------------------------------------------------
// Kernel 0: cast hidden (4M f32) and W (3M f32) to bf16. BW-bound, ~8 us.
// ---------------------------------------------------------------------------
__global__ __launch_bounds__(256) void cast_bf16(
    const float* __restrict__ A, const float* __restrict__ W,
    u16* __restrict__ Ab, u16* __restrict__ Wb)
{
    size_t g = (size_t)blockIdx.x * 256 + threadIdx.x;   // 0..917503
    const float* src; u16* dst;
    if (g < 524288) { src = A + g * 8; dst = Ab + g * 8; }
    else            { size_t h = g - 524288; src = W + h * 8; dst = Wb + h * 8; }
    f32x4 a = *(const f32x4*)src;
    f32x4 b = *(const f32x4*)(src + 4);
    ushort4 lo, hi;
    lo.x = f2bf(a[0]); lo.y = f2bf(a[1]); lo.z = f2bf(a[2]); lo.w = f2bf(a[3]);
    hi.x = f2bf(b[0]); hi.y = f2bf(b[1]); hi.z = f2bf(b[2]); hi.w = f2bf(b[3]);
    *(ushort4*)dst = lo; *(ushort4*)(dst + 4) = hi;
}

// ---------------------------------------------------------------------------
// Kernel 1: QKV GEMM on bf16 inputs, m97-style global_load_lds staging.
// Writes Q[bh][s][d], K[bh][s][d], Vt[bh][d][s].
// ---------------------------------------------------------------------------
__global__ __launch_bounds__(256) void qkv_gemm(
    const u16* __restrict__ Ab, const u16* __restrict__ Wb,
    const float* __restrict__ bias,
    u16* __restrict__ Qb, u16* __restrict__ Kb, u16* __restrict__ Vt)
{
    __shared__ u16 As[128 * 64];
    __shared__ u16 Bs[128 * 64];

    const int tid  = threadIdx.x;
    const int lane = tid & 63;
    const int w    = tid >> 6;
    const int wm   = (w >> 1) * 64;
    const int wn   = (w & 1) * 64;
    const int l15  = lane & 15;
    const int lg   = lane >> 4;
    const int mBase = blockIdx.y * 128;
    const int nBase = blockIdx.x * 128;

    int rS[4], cS[4];
    #pragma unroll
    for (int i = 0; i < 4; ++i) {
        int n = (w * 4 + i) * 64 + lane;
        rS[i] = n >> 3;
        cS[i] = (n & 7) ^ (rS[i] & 7);
    }

    f32x4 acc[4][4] = {};

    for (int kt = 0; kt < 1024; kt += 64) {
        __syncthreads();
        const u16* ab = Ab + (size_t)mBase * 1024 + kt;
        const u16* wb = Wb + (size_t)nBase * 1024 + kt;
        #pragma unroll
        for (int i = 0; i < 4; ++i) {
            GLOAD_LDS16(ab + (size_t)rS[i] * 1024 + cS[i] * 8, As + (w * 4 + i) * 512);
            GLOAD_LDS16(wb + (size_t)rS[i] * 1024 + cS[i] * 8, Bs + (w * 4 + i) * 512);
        }
        __syncthreads();

        #pragma unroll
        for (int kk = 0; kk < 2; ++kk) {
            s16x8 af[4], bfr[4];
            #pragma unroll
            for (int mi = 0; mi < 4; ++mi) {
                int row = wm + mi * 16 + l15;
                int byte = (row * 128 + ((kk * 64 + lg * 16) ^ ((row & 7) << 4)));
                af[mi] = *(const s16x8*)((const char*)As + byte);
            }
            #pragma unroll
            for (int ni = 0; ni < 4; ++ni) {
                int row = wn + ni * 16 + l15;
                int byte = (row * 128 + ((kk * 64 + lg * 16) ^ ((row & 7) << 4)));
                bfr[ni] = *(const s16x8*)((const char*)Bs + byte);
            }
            #pragma unroll
            for (int mi = 0; mi < 4; ++mi)
                #pragma unroll
                for (int ni = 0; ni < 4; ++ni)
                    acc[mi][ni] = __builtin_amdgcn_mfma_f32_16x16x32_bf16(
                        af[mi], bfr[ni], acc[mi][ni], 0, 0, 0);
        }
    }

    #pragma unroll
    for (int ni = 0; ni < 4; ++ni) {
        int gn = nBase + wn + ni * 16 + l15;
        float bv = bias[gn];
        int h  = gn / 192;
        int r  = gn - h * 192;
        int c  = r >> 6;
        int dd = r & 63;
        #pragma unroll
        for (int mi = 0; mi < 4; ++mi) {
            #pragma unroll
            for (int j = 0; j < 4; ++j) {
                int m = mBase + wm + mi * 16 + lg * 4 + j;
                float val = acc[mi][ni][j] + bv;
                int s = m >> 1, b = m & 1;
                int bh = b * 16 + h;
                u16 o = f2bf(val);
                if (c == 0)      Qb[((size_t)bh * S_ + s) * 64 + dd] = o;
                else if (c == 1) Kb[((size_t)bh * S_ + s) * 64 + dd] = o;
                else             Vt[((size_t)bh * 64 + dd) * S_ + s] = o;
            }
        }
    }
}

// ---------------------------------------------------------------------------
// Kernel 2: attention. Identical to R8 except: ALL output stores are plain
// (through-L2) instead of nontemporal — A/B of the NT write path.
// ---------------------------------------------------------------------------
__global__ __launch_bounds__(256, 4) void attn(
    const u16* __restrict__ Qb, const u16* __restrict__ Kb, const u16* __restrict__ Vt,
    const float* __restrict__ mask,
    float* __restrict__ ctx, float* __restrict__ scores, float* __restrict__ probs)
{
    __shared__ u16 Ks[2][64 * 64];     // [t][d] swizzled, 8 KB each
    __shared__ u16 Vs[2][64 * 64];     // [d][t] swizzled, 8 KB each
    __shared__ float SG[4][512];       // per-wave stage [16 q][32 t] f32, 2 KB

    const int tid  = threadIdx.x;
    const int lane = tid & 63;
    const int w    = tid >> 6;
    const int l15  = lane & 15;
    const int lg   = lane >> 4;

    const int lin  = blockIdx.y * 32 + blockIdx.x;
    const int orig = (lin & 7) * 128 + (lin >> 3);
    const int bh   = orig >> 5;
    const int rowQ = (orig & 31) * 64 + w * 16;

    const int nK = (w * 2) * 64 + lane;
    const int rK0 = nK >> 3, cK0 = (nK & 7) ^ (rK0 & 7);
    const int nK1 = nK + 64;
    const int rK1 = nK1 >> 3, cK1 = (nK1 & 7) ^ (rK1 & 7);

    s16x8 qf[2];
    #pragma unroll
    for (int kk = 0; kk < 2; ++kk)
        qf[kk] = *(const s16x8*)(Qb + ((size_t)bh * S_ + rowQ + l15) * 64 + kk * 32 + lg * 8);

    f32x4 cacc[4] = {};

    auto stage = [&](int buf, int tt) {
        const u16* kbase = Kb + (size_t)bh * S_ * 64 + (size_t)tt * 64;
        const u16* vbase = Vt + (size_t)bh * 64 * S_ + tt;
        GLOAD_LDS16(kbase + (size_t)rK0 * 64 + cK0 * 8, &Ks[buf][(w * 2 + 0) * 512]);
        GLOAD_LDS16(kbase + (size_t)rK1 * 64 + cK1 * 8, &Ks[buf][(w * 2 + 1) * 512]);
        GLOAD_LDS16(vbase + (size_t)rK0 * S_ + cK0 * 8, &Vs[buf][(w * 2 + 0) * 512]);
        GLOAD_LDS16(vbase + (size_t)rK1 * S_ + cK1 * 8, &Vs[buf][(w * 2 + 1) * 512]);
    };

    stage(0, 0);
    __syncthreads();
    int cur = 0;

    const int q = rowQ + l15;
    const float* mrow = mask + (size_t)q * S_;

    const int rdq   = lane >> 3;
    const int rslot = lane & 7;
    const int s0 = (lg >> 1) * 4 + (lg & 1) * 2;
    const int pvbyteA = l15 * 128 + (((s0 + 0) * 16) ^ ((l15 & 7) << 4));
    const int pvbyteB = l15 * 128 + (((s0 + 1) * 16) ^ ((l15 & 7) << 4));

    for (int tt = 0; tt < S_; tt += 64) {
        if (tt + 64 < S_) stage(cur ^ 1, tt + 64);

        f32x4 mv[4];
        #pragma unroll
        for (int tb = 0; tb < 4; ++tb)
            mv[tb] = *(const f32x4*)(mrow + tt + tb * 16 + lg * 4);

        f32x4 sacc[4] = {};
        #pragma unroll
        for (int kk = 0; kk < 2; ++kk) {
            #pragma unroll
            for (int tb = 0; tb < 4; ++tb) {
                int row = tb * 16 + l15;
                int byte = (row * 128 + ((kk * 64 + lg * 16) ^ ((row & 7) << 4)));
                s16x8 kf = *(const s16x8*)((const char*)Ks[cur] + byte);
                sacc[tb] = __builtin_amdgcn_mfma_f32_16x16x32_bf16(
                    kf, qf[kk], sacc[tb], 0, 0, 0);
            }
        }

        #pragma unroll
        for (int kv = 0; kv < 2; ++kv) {
            f32x4 s4[2], p4[2];
            #pragma unroll
            for (int th = 0; th < 2; ++th) {
                int tb = kv * 2 + th;
                f32x4 sc = sacc[tb];
                s4[th][0] = sc[0] * 0.125f + mv[tb][0];
                s4[th][1] = sc[1] * 0.125f + mv[tb][1];
                s4[th][2] = sc[2] * 0.125f + mv[tb][2];
                s4[th][3] = sc[3] * 0.125f + mv[tb][3];
                int sbyte = l15 * 128 + (((th * 4 + lg) * 16) ^ ((l15 & 7) << 4));
                *(f32x4*)((char*)SG[w] + sbyte) = s4[th];
            }
            #pragma unroll
            for (int p = 0; p < 2; ++p) {
                int qq = p * 8 + rdq;
                int rbyte = qq * 128 + ((rslot * 16) ^ ((qq & 7) << 4));
                f32x4 v = *(const f32x4*)((const char*)SG[w] + rbyte);
                *(f32x4*)(scores +
                    (size_t)bh * S_ * S_ + (size_t)(rowQ + qq) * S_ + tt + kv * 32 + rslot * 4) = v;
            }
            #pragma unroll
            for (int th = 0; th < 2; ++th) {
                p4[th][0] = __expf(s4[th][0]); p4[th][1] = __expf(s4[th][1]);
                p4[th][2] = __expf(s4[th][2]); p4[th][3] = __expf(s4[th][3]);
                int sbyte = l15 * 128 + (((th * 4 + lg) * 16) ^ ((l15 & 7) << 4));
                *(f32x4*)((char*)SG[w] + sbyte) = p4[th];
            }
            #pragma unroll
            for (int p = 0; p < 2; ++p) {
                int qq = p * 8 + rdq;
                int rbyte = qq * 128 + ((rslot * 16) ^ ((qq & 7) << 4));
                f32x4 v = *(const f32x4*)((const char*)SG[w] + rbyte);
                *(f32x4*)(probs +
                    (size_t)bh * S_ * S_ + (size_t)(rowQ + qq) * S_ + tt + kv * 32 + rslot * 4) = v;
            }
            f32x4 ra = *(const f32x4*)((const char*)SG[w] + pvbyteA);
            f32x4 rb = *(const f32x4*)((const char*)SG[w] + pvbyteB);
            unsigned int w0, w1, w2, w3;
            asm("v_cvt_pk_bf16_f32 %0, %1, %2" : "=v"(w0) : "v"(ra[0]), "v"(ra[1]));
            asm("v_cvt_pk_bf16_f32 %0, %1, %2" : "=v"(w1) : "v"(ra[2]), "v"(ra[3]));
            asm("v_cvt_pk_bf16_f32 %0, %1, %2" : "=v"(w2) : "v"(rb[0]), "v"(rb[1]));
            asm("v_cvt_pk_bf16_f32 %0, %1, %2" : "=v"(w3) : "v"(rb[2]), "v"(rb[3]));
            union { unsigned int u[4]; s16x8 v; } pk;
            pk.u[0] = w0; pk.u[1] = w1; pk.u[2] = w2; pk.u[3] = w3;
            s16x8 pa = pk.v;
            #pragma unroll
            for (int db = 0; db < 4; ++db) {
                int row = db * 16 + l15;
                int byte = (row * 128 + ((kv * 64 + lg * 16) ^ ((row & 7) << 4)));
                s16x8 vb = *(const s16x8*)((const char*)Vs[cur] + byte);
                cacc[db] = __builtin_amdgcn_mfma_f32_16x16x32_bf16(
                    pa, vb, cacc[db], 0, 0, 0);
            }
        }

        asm volatile("s_waitcnt vmcnt(8) lgkmcnt(0)" ::: "memory");
        __builtin_amdgcn_s_barrier();
        cur ^= 1;
    }

    const int b = bh >> 4, h = bh & 15;
    #pragma unroll
    for (int db = 0; db < 4; ++db)
        #pragma unroll
        for (int j = 0; j < 4; ++j) {
            int srow = rowQ + lg * 4 + j;
            int dd = db * 16 + l15;
            ctx[((size_t)srow * B_ + b) * H_ + h * 64 + dd] = cacc[db][j];
        }
}

extern "C" void kernel_launch(void* const* d_in, const int* in_sizes, int n_in,
                              void* d_out, int out_size, void* d_ws, size_t ws_size,
                              hipStream_t stream) {
    const float* hidden = (const float*)d_in[0];
    const float* mask   = (const float*)d_in[1];
    const float* W      = (const float*)d_in[2];
    const float* bias   = (const float*)d_in[3];

    u16* Qb = (u16*)d_ws;
    u16* Kb = Qb + 4194304;
    u16* Vt = Kb + 4194304;

    float* out    = (float*)d_out;
    float* ctx    = out;
    float* scores = out + 4194304;
    float* probs  = out + 138412032;

    u16* Ab = (u16*)scores;            // bf16 temps in not-yet-written scores region
    u16* Wb = Ab + 4194304;

    cast_bf16<<<dim3(3584), 256, 0, stream>>>(hidden, W, Ab, Wb);
    qkv_gemm<<<dim3(24, 32), 256, 0, stream>>>(Ab, Wb, bias, Qb, Kb, Vt);
    attn<<<dim3(32, 32), 256, 0, stream>>>(Qb, Kb, Vt, mask, ctx, scores, probs);
}

// Round 10
// 294.454 us; speedup vs baseline: 1.0926x; 1.0926x over previous
//
#include <hip/hip_runtime.h>
#include <hip/hip_bf16.h>

#define S_  2048
#define B_  2
#define H_  1024
#define NH_ 16
#define D_  64

typedef short s16x8 __attribute__((ext_vector_type(8)));
typedef float f32x4 __attribute__((ext_vector_type(4)));
typedef unsigned short u16;

__device__ __forceinline__ u16 f2bf(float f) {
    __hip_bfloat16 h = __float2bfloat16(f);
    union { __hip_bfloat16 h; u16 u; } c; c.h = h; return c.u;
}

#define GLOAD_LDS16(g, l) __builtin_amdgcn_global_load_lds( \
    (const __attribute__((address_space(1))) void*)(g),     \
    (__attribute__((address_space(3))) void*)(l), 16, 0, 0)

// ---------------------------------------------------------------------------
// Kernel 0: cast hidden (4M f32) and W (3M f32) to bf16. BW-bound, ~8 us.
// ---------------------------------------------------------------------------
__global__ __launch_bounds__(256) void cast_bf16(
    const float* __restrict__ A, const float* __restrict__ W,
    u16* __restrict__ Ab, u16* __restrict__ Wb)
{
    size_t g = (size_t)blockIdx.x * 256 + threadIdx.x;   // 0..917503
    const float* src; u16* dst;
    if (g < 524288) { src = A + g * 8; dst = Ab + g * 8; }
    else            { size_t h = g - 524288; src = W + h * 8; dst = Wb + h * 8; }
    f32x4 a = *(const f32x4*)src;
    f32x4 b = *(const f32x4*)(src + 4);
    ushort4 lo, hi;
    lo.x = f2bf(a[0]); lo.y = f2bf(a[1]); lo.z = f2bf(a[2]); lo.w = f2bf(a[3]);
    hi.x = f2bf(b[0]); hi.y = f2bf(b[1]); hi.z = f2bf(b[2]); hi.w = f2bf(b[3]);
    *(ushort4*)dst = lo; *(ushort4*)(dst + 4) = hi;
}

// ---------------------------------------------------------------------------
// Kernel 1: QKV GEMM, bf16 inputs, global_load_lds staging. NEW: double-
// buffered LDS + counted vmcnt(8) — stage(k+1) stays in flight across
// compute(k) and both barriers; no per-K-step full drain.
// ---------------------------------------------------------------------------
__global__ __launch_bounds__(256) void qkv_gemm(
    const u16* __restrict__ Ab, const u16* __restrict__ Wb,
    const float* __restrict__ bias,
    u16* __restrict__ Qb, u16* __restrict__ Kb, u16* __restrict__ Vt)
{
    __shared__ u16 As[2][128 * 64];   // 16 KB each
    __shared__ u16 Bs[2][128 * 64];

    const int tid  = threadIdx.x;
    const int lane = tid & 63;
    const int w    = tid >> 6;
    const int wm   = (w >> 1) * 64;
    const int wn   = (w & 1) * 64;
    const int l15  = lane & 15;
    const int lg   = lane >> 4;
    const int mBase = blockIdx.y * 128;
    const int nBase = blockIdx.x * 128;

    int rS[4], cS[4];
    #pragma unroll
    for (int i = 0; i < 4; ++i) {
        int n = (w * 4 + i) * 64 + lane;
        rS[i] = n >> 3;
        cS[i] = (n & 7) ^ (rS[i] & 7);
    }

    auto stage = [&](int buf, int kt) {
        const u16* ab = Ab + (size_t)mBase * 1024 + kt;
        const u16* wb = Wb + (size_t)nBase * 1024 + kt;
        #pragma unroll
        for (int i = 0; i < 4; ++i) {
            GLOAD_LDS16(ab + (size_t)rS[i] * 1024 + cS[i] * 8, &As[buf][(w * 4 + i) * 512]);
            GLOAD_LDS16(wb + (size_t)rS[i] * 1024 + cS[i] * 8, &Bs[buf][(w * 4 + i) * 512]);
        }
    };

    f32x4 acc[4][4] = {};

    stage(0, 0);
    __syncthreads();                  // prologue: full drain, tile 0 in LDS

    for (int it = 0; it < 16; ++it) {
        const int cur = it & 1;
        const int kt  = it * 64;
        if (it > 0)
            __builtin_amdgcn_s_barrier();          // prev readers done -> may overwrite buf cur^1
        if (it < 15) {
            stage(cur ^ 1, kt + 64);               // +8 gloads, fly across compute
            if (it > 0)
                asm volatile("s_waitcnt vmcnt(8)" ::: "memory");   // stage(cur) retired
        } else {
            asm volatile("s_waitcnt vmcnt(0)" ::: "memory");       // last tile: drain
        }
        __builtin_amdgcn_s_barrier();              // all waves: buf cur ready

        #pragma unroll
        for (int kk = 0; kk < 2; ++kk) {
            s16x8 af[4], bfr[4];
            #pragma unroll
            for (int mi = 0; mi < 4; ++mi) {
                int row = wm + mi * 16 + l15;
                int byte = (row * 128 + ((kk * 64 + lg * 16) ^ ((row & 7) << 4)));
                af[mi] = *(const s16x8*)((const char*)As[cur] + byte);
            }
            #pragma unroll
            for (int ni = 0; ni < 4; ++ni) {
                int row = wn + ni * 16 + l15;
                int byte = (row * 128 + ((kk * 64 + lg * 16) ^ ((row & 7) << 4)));
                bfr[ni] = *(const s16x8*)((const char*)Bs[cur] + byte);
            }
            #pragma unroll
            for (int mi = 0; mi < 4; ++mi)
                #pragma unroll
                for (int ni = 0; ni < 4; ++ni)
                    acc[mi][ni] = __builtin_amdgcn_mfma_f32_16x16x32_bf16(
                        af[mi], bfr[ni], acc[mi][ni], 0, 0, 0);
        }
    }

    #pragma unroll
    for (int ni = 0; ni < 4; ++ni) {
        int gn = nBase + wn + ni * 16 + l15;
        float bv = bias[gn];
        int h  = gn / 192;
        int r  = gn - h * 192;
        int c  = r >> 6;
        int dd = r & 63;
        #pragma unroll
        for (int mi = 0; mi < 4; ++mi) {
            #pragma unroll
            for (int j = 0; j < 4; ++j) {
                int m = mBase + wm + mi * 16 + lg * 4 + j;
                float val = acc[mi][ni][j] + bv;
                int s = m >> 1, b = m & 1;
                int bh = b * 16 + h;
                u16 o = f2bf(val);
                if (c == 0)      Qb[((size_t)bh * S_ + s) * 64 + dd] = o;
                else if (c == 1) Kb[((size_t)bh * S_ + s) * 64 + dd] = o;
                else             Vt[((size_t)bh * 64 + dd) * S_ + s] = o;
            }
        }
    }
}

// ---------------------------------------------------------------------------
// Kernel 2: attention — identical to R8 (NT stores restored; R9's plain
// stores regressed 24 us).
// ---------------------------------------------------------------------------
__global__ __launch_bounds__(256, 4) void attn(
    const u16* __restrict__ Qb, const u16* __restrict__ Kb, const u16* __restrict__ Vt,
    const float* __restrict__ mask,
    float* __restrict__ ctx, float* __restrict__ scores, float* __restrict__ probs)
{
    __shared__ u16 Ks[2][64 * 64];     // [t][d] swizzled, 8 KB each
    __shared__ u16 Vs[2][64 * 64];     // [d][t] swizzled, 8 KB each
    __shared__ float SG[4][512];       // per-wave stage [16 q][32 t] f32, 2 KB

    const int tid  = threadIdx.x;
    const int lane = tid & 63;
    const int w    = tid >> 6;
    const int l15  = lane & 15;
    const int lg   = lane >> 4;

    const int lin  = blockIdx.y * 32 + blockIdx.x;
    const int orig = (lin & 7) * 128 + (lin >> 3);
    const int bh   = orig >> 5;
    const int rowQ = (orig & 31) * 64 + w * 16;

    const int nK = (w * 2) * 64 + lane;
    const int rK0 = nK >> 3, cK0 = (nK & 7) ^ (rK0 & 7);
    const int nK1 = nK + 64;
    const int rK1 = nK1 >> 3, cK1 = (nK1 & 7) ^ (rK1 & 7);

    s16x8 qf[2];
    #pragma unroll
    for (int kk = 0; kk < 2; ++kk)
        qf[kk] = *(const s16x8*)(Qb + ((size_t)bh * S_ + rowQ + l15) * 64 + kk * 32 + lg * 8);

    f32x4 cacc[4] = {};

    auto stage = [&](int buf, int tt) {
        const u16* kbase = Kb + (size_t)bh * S_ * 64 + (size_t)tt * 64;
        const u16* vbase = Vt + (size_t)bh * 64 * S_ + tt;
        GLOAD_LDS16(kbase + (size_t)rK0 * 64 + cK0 * 8, &Ks[buf][(w * 2 + 0) * 512]);
        GLOAD_LDS16(kbase + (size_t)rK1 * 64 + cK1 * 8, &Ks[buf][(w * 2 + 1) * 512]);
        GLOAD_LDS16(vbase + (size_t)rK0 * S_ + cK0 * 8, &Vs[buf][(w * 2 + 0) * 512]);
        GLOAD_LDS16(vbase + (size_t)rK1 * S_ + cK1 * 8, &Vs[buf][(w * 2 + 1) * 512]);
    };

    stage(0, 0);
    __syncthreads();
    int cur = 0;

    const int q = rowQ + l15;
    const float* mrow = mask + (size_t)q * S_;

    const int rdq   = lane >> 3;
    const int rslot = lane & 7;
    const int s0 = (lg >> 1) * 4 + (lg & 1) * 2;
    const int pvbyteA = l15 * 128 + (((s0 + 0) * 16) ^ ((l15 & 7) << 4));
    const int pvbyteB = l15 * 128 + (((s0 + 1) * 16) ^ ((l15 & 7) << 4));

    for (int tt = 0; tt < S_; tt += 64) {
        if (tt + 64 < S_) stage(cur ^ 1, tt + 64);

        f32x4 mv[4];
        #pragma unroll
        for (int tb = 0; tb < 4; ++tb)
            mv[tb] = *(const f32x4*)(mrow + tt + tb * 16 + lg * 4);

        f32x4 sacc[4] = {};
        #pragma unroll
        for (int kk = 0; kk < 2; ++kk) {
            #pragma unroll
            for (int tb = 0; tb < 4; ++tb) {
                int row = tb * 16 + l15;
                int byte = (row * 128 + ((kk * 64 + lg * 16) ^ ((row & 7) << 4)));
                s16x8 kf = *(const s16x8*)((const char*)Ks[cur] + byte);
                sacc[tb] = __builtin_amdgcn_mfma_f32_16x16x32_bf16(
                    kf, qf[kk], sacc[tb], 0, 0, 0);
            }
        }

        #pragma unroll
        for (int kv = 0; kv < 2; ++kv) {
            f32x4 s4[2], p4[2];
            #pragma unroll
            for (int th = 0; th < 2; ++th) {
                int tb = kv * 2 + th;
                f32x4 sc = sacc[tb];
                s4[th][0] = sc[0] * 0.125f + mv[tb][0];
                s4[th][1] = sc[1] * 0.125f + mv[tb][1];
                s4[th][2] = sc[2] * 0.125f + mv[tb][2];
                s4[th][3] = sc[3] * 0.125f + mv[tb][3];
                int sbyte = l15 * 128 + (((th * 4 + lg) * 16) ^ ((l15 & 7) << 4));
                *(f32x4*)((char*)SG[w] + sbyte) = s4[th];
            }
            #pragma unroll
            for (int p = 0; p < 2; ++p) {
                int qq = p * 8 + rdq;
                int rbyte = qq * 128 + ((rslot * 16) ^ ((qq & 7) << 4));
                f32x4 v = *(const f32x4*)((const char*)SG[w] + rbyte);
                __builtin_nontemporal_store(v, (f32x4*)(scores +
                    (size_t)bh * S_ * S_ + (size_t)(rowQ + qq) * S_ + tt + kv * 32 + rslot * 4));
            }
            #pragma unroll
            for (int th = 0; th < 2; ++th) {
                p4[th][0] = __expf(s4[th][0]); p4[th][1] = __expf(s4[th][1]);
                p4[th][2] = __expf(s4[th][2]); p4[th][3] = __expf(s4[th][3]);
                int sbyte = l15 * 128 + (((th * 4 + lg) * 16) ^ ((l15 & 7) << 4));
                *(f32x4*)((char*)SG[w] + sbyte) = p4[th];
            }
            #pragma unroll
            for (int p = 0; p < 2; ++p) {
                int qq = p * 8 + rdq;
                int rbyte = qq * 128 + ((rslot * 16) ^ ((qq & 7) << 4));
                f32x4 v = *(const f32x4*)((const char*)SG[w] + rbyte);
                __builtin_nontemporal_store(v, (f32x4*)(probs +
                    (size_t)bh * S_ * S_ + (size_t)(rowQ + qq) * S_ + tt + kv * 32 + rslot * 4));
            }
            f32x4 ra = *(const f32x4*)((const char*)SG[w] + pvbyteA);
            f32x4 rb = *(const f32x4*)((const char*)SG[w] + pvbyteB);
            unsigned int w0, w1, w2, w3;
            asm("v_cvt_pk_bf16_f32 %0, %1, %2" : "=v"(w0) : "v"(ra[0]), "v"(ra[1]));
            asm("v_cvt_pk_bf16_f32 %0, %1, %2" : "=v"(w1) : "v"(ra[2]), "v"(ra[3]));
            asm("v_cvt_pk_bf16_f32 %0, %1, %2" : "=v"(w2) : "v"(rb[0]), "v"(rb[1]));
            asm("v_cvt_pk_bf16_f32 %0, %1, %2" : "=v"(w3) : "v"(rb[2]), "v"(rb[3]));
            union { unsigned int u[4]; s16x8 v; } pk;
            pk.u[0] = w0; pk.u[1] = w1; pk.u[2] = w2; pk.u[3] = w3;
            s16x8 pa = pk.v;
            #pragma unroll
            for (int db = 0; db < 4; ++db) {
                int row = db * 16 + l15;
                int byte = (row * 128 + ((kv * 64 + lg * 16) ^ ((row & 7) << 4)));
                s16x8 vb = *(const s16x8*)((const char*)Vs[cur] + byte);
                cacc[db] = __builtin_amdgcn_mfma_f32_16x16x32_bf16(
                    pa, vb, cacc[db], 0, 0, 0);
            }
        }

        asm volatile("s_waitcnt vmcnt(8) lgkmcnt(0)" ::: "memory");
        __builtin_amdgcn_s_barrier();
        cur ^= 1;
    }

    const int b = bh >> 4, h = bh & 15;
    #pragma unroll
    for (int db = 0; db < 4; ++db)
        #pragma unroll
        for (int j = 0; j < 4; ++j) {
            int srow = rowQ + lg * 4 + j;
            int dd = db * 16 + l15;
            __builtin_nontemporal_store(cacc[db][j],
                ctx + ((size_t)srow * B_ + b) * H_ + h * 64 + dd);
        }
}

extern "C" void kernel_launch(void* const* d_in, const int* in_sizes, int n_in,
                              void* d_out, int out_size, void* d_ws, size_t ws_size,
                              hipStream_t stream) {
    const float* hidden = (const float*)d_in[0];
    const float* mask   = (const float*)d_in[1];
    const float* W      = (const float*)d_in[2];
    const float* bias   = (const float*)d_in[3];

    u16* Qb = (u16*)d_ws;
    u16* Kb = Qb + 4194304;
    u16* Vt = Kb + 4194304;

    float* out    = (float*)d_out;
    float* ctx    = out;
    float* scores = out + 4194304;
    float* probs  = out + 138412032;

    u16* Ab = (u16*)scores;            // bf16 temps in not-yet-written scores region
    u16* Wb = Ab + 4194304;

    cast_bf16<<<dim3(3584), 256, 0, stream>>>(hidden, W, Ab, Wb);
    qkv_gemm<<<dim3(24, 32), 256, 0, stream>>>(Ab, Wb, bias, Qb, Kb, Vt);
    attn<<<dim3(32, 32), 256, 0, stream>>>(Qb, Kb, Vt, mask, ctx, scores, probs);
}

// Round 11
// 291.626 us; speedup vs baseline: 1.1032x; 1.0097x over previous
//
#include <hip/hip_runtime.h>
#include <hip/hip_bf16.h>

#define S_  2048
#define B_  2
#define H_  1024
#define NH_ 16
#define D_  64

typedef short s16x8 __attribute__((ext_vector_type(8)));
typedef float f32x4 __attribute__((ext_vector_type(4)));
typedef unsigned short u16;

__device__ __forceinline__ u16 f2bf(float f) {
    __hip_bfloat16 h = __float2bfloat16(f);
    union { __hip_bfloat16 h; u16 u; } c; c.h = h; return c.u;
}

#define GLOAD_LDS16(g, l) __builtin_amdgcn_global_load_lds( \
    (const __attribute__((address_space(1))) void*)(g),     \
    (__attribute__((address_space(3))) void*)(l), 16, 0, 0)

// ---------------------------------------------------------------------------
// Kernel 0: cast hidden (4M f32) and W (3M f32) to bf16. BW-bound, ~8 us.
// ---------------------------------------------------------------------------
__global__ __launch_bounds__(256) void cast_bf16(
    const float* __restrict__ A, const float* __restrict__ W,
    u16* __restrict__ Ab, u16* __restrict__ Wb)
{
    size_t g = (size_t)blockIdx.x * 256 + threadIdx.x;   // 0..917503
    const float* src; u16* dst;
    if (g < 524288) { src = A + g * 8; dst = Ab + g * 8; }
    else            { size_t h = g - 524288; src = W + h * 8; dst = Wb + h * 8; }
    f32x4 a = *(const f32x4*)src;
    f32x4 b = *(const f32x4*)(src + 4);
    ushort4 lo, hi;
    lo.x = f2bf(a[0]); lo.y = f2bf(a[1]); lo.z = f2bf(a[2]); lo.w = f2bf(a[3]);
    hi.x = f2bf(b[0]); hi.y = f2bf(b[1]); hi.z = f2bf(b[2]); hi.w = f2bf(b[3]);
    *(ushort4*)dst = lo; *(ushort4*)(dst + 4) = hi;
}

// ---------------------------------------------------------------------------
// Kernel 1: QKV GEMM (unchanged from R10: dbuf + counted vmcnt(8)).
// ---------------------------------------------------------------------------
__global__ __launch_bounds__(256) void qkv_gemm(
    const u16* __restrict__ Ab, const u16* __restrict__ Wb,
    const float* __restrict__ bias,
    u16* __restrict__ Qb, u16* __restrict__ Kb, u16* __restrict__ Vt)
{
    __shared__ u16 As[2][128 * 64];
    __shared__ u16 Bs[2][128 * 64];

    const int tid  = threadIdx.x;
    const int lane = tid & 63;
    const int w    = tid >> 6;
    const int wm   = (w >> 1) * 64;
    const int wn   = (w & 1) * 64;
    const int l15  = lane & 15;
    const int lg   = lane >> 4;
    const int mBase = blockIdx.y * 128;
    const int nBase = blockIdx.x * 128;

    int rS[4], cS[4];
    #pragma unroll
    for (int i = 0; i < 4; ++i) {
        int n = (w * 4 + i) * 64 + lane;
        rS[i] = n >> 3;
        cS[i] = (n & 7) ^ (rS[i] & 7);
    }

    auto stage = [&](int buf, int kt) {
        const u16* ab = Ab + (size_t)mBase * 1024 + kt;
        const u16* wb = Wb + (size_t)nBase * 1024 + kt;
        #pragma unroll
        for (int i = 0; i < 4; ++i) {
            GLOAD_LDS16(ab + (size_t)rS[i] * 1024 + cS[i] * 8, &As[buf][(w * 4 + i) * 512]);
            GLOAD_LDS16(wb + (size_t)rS[i] * 1024 + cS[i] * 8, &Bs[buf][(w * 4 + i) * 512]);
        }
    };

    f32x4 acc[4][4] = {};

    stage(0, 0);
    __syncthreads();

    for (int it = 0; it < 16; ++it) {
        const int cur = it & 1;
        const int kt  = it * 64;
        if (it > 0)
            __builtin_amdgcn_s_barrier();
        if (it < 15) {
            stage(cur ^ 1, kt + 64);
            if (it > 0)
                asm volatile("s_waitcnt vmcnt(8)" ::: "memory");
        } else {
            asm volatile("s_waitcnt vmcnt(0)" ::: "memory");
        }
        __builtin_amdgcn_s_barrier();

        #pragma unroll
        for (int kk = 0; kk < 2; ++kk) {
            s16x8 af[4], bfr[4];
            #pragma unroll
            for (int mi = 0; mi < 4; ++mi) {
                int row = wm + mi * 16 + l15;
                int byte = (row * 128 + ((kk * 64 + lg * 16) ^ ((row & 7) << 4)));
                af[mi] = *(const s16x8*)((const char*)As[cur] + byte);
            }
            #pragma unroll
            for (int ni = 0; ni < 4; ++ni) {
                int row = wn + ni * 16 + l15;
                int byte = (row * 128 + ((kk * 64 + lg * 16) ^ ((row & 7) << 4)));
                bfr[ni] = *(const s16x8*)((const char*)Bs[cur] + byte);
            }
            #pragma unroll
            for (int mi = 0; mi < 4; ++mi)
                #pragma unroll
                for (int ni = 0; ni < 4; ++ni)
                    acc[mi][ni] = __builtin_amdgcn_mfma_f32_16x16x32_bf16(
                        af[mi], bfr[ni], acc[mi][ni], 0, 0, 0);
        }
    }

    #pragma unroll
    for (int ni = 0; ni < 4; ++ni) {
        int gn = nBase + wn + ni * 16 + l15;
        float bv = bias[gn];
        int h  = gn / 192;
        int r  = gn - h * 192;
        int c  = r >> 6;
        int dd = r & 63;
        #pragma unroll
        for (int mi = 0; mi < 4; ++mi) {
            #pragma unroll
            for (int j = 0; j < 4; ++j) {
                int m = mBase + wm + mi * 16 + lg * 4 + j;
                float val = acc[mi][ni][j] + bv;
                int s = m >> 1, b = m & 1;
                int bh = b * 16 + h;
                u16 o = f2bf(val);
                if (c == 0)      Qb[((size_t)bh * S_ + s) * 64 + dd] = o;
                else if (c == 1) Kb[((size_t)bh * S_ + s) * 64 + dd] = o;
                else             Vt[((size_t)bh * 64 + dd) * S_ + s] = o;
            }
        }
    }
}

// ---------------------------------------------------------------------------
// Kernel 2: attention. NEW vs R8/R10: SG enlarged to [16 q][64 t] f32 (4 KB
// per wave) — whole 64-t tile staged per output, readback with 16 lanes/row
// x 4 rows/instr -> 256B contiguous segments per NT store (was 128B).
// LDS 48 KB -> 3 blocks/CU.
// ---------------------------------------------------------------------------
__global__ __launch_bounds__(256, 3) void attn(
    const u16* __restrict__ Qb, const u16* __restrict__ Kb, const u16* __restrict__ Vt,
    const float* __restrict__ mask,
    float* __restrict__ ctx, float* __restrict__ scores, float* __restrict__ probs)
{
    __shared__ u16 Ks[2][64 * 64];     // [t][d] swizzled, 8 KB each
    __shared__ u16 Vs[2][64 * 64];     // [d][t] swizzled, 8 KB each
    __shared__ float SG[4][1024];      // per-wave stage [16 q][64 t] f32, 4 KB

    const int tid  = threadIdx.x;
    const int lane = tid & 63;
    const int w    = tid >> 6;
    const int l15  = lane & 15;
    const int lg   = lane >> 4;

    const int lin  = blockIdx.y * 32 + blockIdx.x;
    const int orig = (lin & 7) * 128 + (lin >> 3);
    const int bh   = orig >> 5;
    const int rowQ = (orig & 31) * 64 + w * 16;

    const int nK = (w * 2) * 64 + lane;
    const int rK0 = nK >> 3, cK0 = (nK & 7) ^ (rK0 & 7);
    const int nK1 = nK + 64;
    const int rK1 = nK1 >> 3, cK1 = (nK1 & 7) ^ (rK1 & 7);

    s16x8 qf[2];
    #pragma unroll
    for (int kk = 0; kk < 2; ++kk)
        qf[kk] = *(const s16x8*)(Qb + ((size_t)bh * S_ + rowQ + l15) * 64 + kk * 32 + lg * 8);

    f32x4 cacc[4] = {};

    auto stage = [&](int buf, int tt) {
        const u16* kbase = Kb + (size_t)bh * S_ * 64 + (size_t)tt * 64;
        const u16* vbase = Vt + (size_t)bh * 64 * S_ + tt;
        GLOAD_LDS16(kbase + (size_t)rK0 * 64 + cK0 * 8, &Ks[buf][(w * 2 + 0) * 512]);
        GLOAD_LDS16(kbase + (size_t)rK1 * 64 + cK1 * 8, &Ks[buf][(w * 2 + 1) * 512]);
        GLOAD_LDS16(vbase + (size_t)rK0 * S_ + cK0 * 8, &Vs[buf][(w * 2 + 0) * 512]);
        GLOAD_LDS16(vbase + (size_t)rK1 * S_ + cK1 * 8, &Vs[buf][(w * 2 + 1) * 512]);
    };

    stage(0, 0);
    __syncthreads();
    int cur = 0;

    const float* mrow = mask + (size_t)(rowQ + l15) * S_;

    // readback mapping: 16 lanes/row (256B), 4 rows/instr, 4 passes
    const int rrow  = lane >> 4;          // 0..3, += 4 per pass
    const int rslot = lane & 15;          // 16B slot within 256B row
    // PV fragment slots: lane needs P[q=l15][t' = kv*32 + lg*8 .. +7]
    const int pvs0 = lg * 2;              // + kv*8; two consecutive 16B slots

    for (int tt = 0; tt < S_; tt += 64) {
        if (tt + 64 < S_) stage(cur ^ 1, tt + 64);

        f32x4 mv[4];
        #pragma unroll
        for (int tb = 0; tb < 4; ++tb)
            mv[tb] = *(const f32x4*)(mrow + tt + tb * 16 + lg * 4);

        // QK^T swapped: sacc[tb] = D[t = tb*16+lg*4+j][q = l15]
        f32x4 sacc[4] = {};
        #pragma unroll
        for (int kk = 0; kk < 2; ++kk) {
            #pragma unroll
            for (int tb = 0; tb < 4; ++tb) {
                int row = tb * 16 + l15;
                int byte = (row * 128 + ((kk * 64 + lg * 16) ^ ((row & 7) << 4)));
                s16x8 kf = *(const s16x8*)((const char*)Ks[cur] + byte);
                sacc[tb] = __builtin_amdgcn_mfma_f32_16x16x32_bf16(
                    kf, qf[kk], sacc[tb], 0, 0, 0);
            }
        }

        // ---- scores: stage whole 64-t tile, then 4x 256B-segment NT stores
        f32x4 s4[4];
        #pragma unroll
        for (int tb = 0; tb < 4; ++tb) {
            f32x4 sc = sacc[tb];
            s4[tb][0] = sc[0] * 0.125f + mv[tb][0];
            s4[tb][1] = sc[1] * 0.125f + mv[tb][1];
            s4[tb][2] = sc[2] * 0.125f + mv[tb][2];
            s4[tb][3] = sc[3] * 0.125f + mv[tb][3];
            int sbyte = l15 * 256 + (((tb * 4 + lg) * 16) ^ ((l15 & 7) << 4));
            *(f32x4*)((char*)SG[w] + sbyte) = s4[tb];
        }
        #pragma unroll
        for (int p = 0; p < 4; ++p) {
            int qq = p * 4 + rrow;
            int rbyte = qq * 256 + ((rslot * 16) ^ ((qq & 7) << 4));
            f32x4 v = *(const f32x4*)((const char*)SG[w] + rbyte);
            __builtin_nontemporal_store(v, (f32x4*)(scores +
                (size_t)bh * S_ * S_ + (size_t)(rowQ + qq) * S_ + tt + rslot * 4));
        }

        // ---- probs: exp, stage, 4x 256B-segment NT stores
        f32x4 p4[4];
        #pragma unroll
        for (int tb = 0; tb < 4; ++tb) {
            p4[tb][0] = __expf(s4[tb][0]); p4[tb][1] = __expf(s4[tb][1]);
            p4[tb][2] = __expf(s4[tb][2]); p4[tb][3] = __expf(s4[tb][3]);
            int sbyte = l15 * 256 + (((tb * 4 + lg) * 16) ^ ((l15 & 7) << 4));
            *(f32x4*)((char*)SG[w] + sbyte) = p4[tb];
        }
        #pragma unroll
        for (int p = 0; p < 4; ++p) {
            int qq = p * 4 + rrow;
            int rbyte = qq * 256 + ((rslot * 16) ^ ((qq & 7) << 4));
            f32x4 v = *(const f32x4*)((const char*)SG[w] + rbyte);
            __builtin_nontemporal_store(v, (f32x4*)(probs +
                (size_t)bh * S_ * S_ + (size_t)(rowQ + qq) * S_ + tt + rslot * 4));
        }

        // ---- PV: fragments from SG (probs f32) + cvt_pk pack, per 32-t kv
        #pragma unroll
        for (int kv = 0; kv < 2; ++kv) {
            int slotA = kv * 8 + pvs0;
            int byteA = l15 * 256 + (((slotA + 0) * 16) ^ ((l15 & 7) << 4));
            int byteB = l15 * 256 + (((slotA + 1) * 16) ^ ((l15 & 7) << 4));
            f32x4 ra = *(const f32x4*)((const char*)SG[w] + byteA);
            f32x4 rb = *(const f32x4*)((const char*)SG[w] + byteB);
            unsigned int w0, w1, w2, w3;
            asm("v_cvt_pk_bf16_f32 %0, %1, %2" : "=v"(w0) : "v"(ra[0]), "v"(ra[1]));
            asm("v_cvt_pk_bf16_f32 %0, %1, %2" : "=v"(w1) : "v"(ra[2]), "v"(ra[3]));
            asm("v_cvt_pk_bf16_f32 %0, %1, %2" : "=v"(w2) : "v"(rb[0]), "v"(rb[1]));
            asm("v_cvt_pk_bf16_f32 %0, %1, %2" : "=v"(w3) : "v"(rb[2]), "v"(rb[3]));
            union { unsigned int u[4]; s16x8 v; } pk;
            pk.u[0] = w0; pk.u[1] = w1; pk.u[2] = w2; pk.u[3] = w3;
            s16x8 pa = pk.v;
            #pragma unroll
            for (int db = 0; db < 4; ++db) {
                int row = db * 16 + l15;
                int byte = (row * 128 + ((kv * 64 + lg * 16) ^ ((row & 7) << 4)));
                s16x8 vb = *(const s16x8*)((const char*)Vs[cur] + byte);
                cacc[db] = __builtin_amdgcn_mfma_f32_16x16x32_bf16(
                    pa, vb, cacc[db], 0, 0, 0);
            }
        }

        // counted-vmcnt barrier: [4 gload][4 mask] retired; 8 NT stores fly.
        asm volatile("s_waitcnt vmcnt(8) lgkmcnt(0)" ::: "memory");
        __builtin_amdgcn_s_barrier();
        cur ^= 1;
    }

    const int b = bh >> 4, h = bh & 15;
    #pragma unroll
    for (int db = 0; db < 4; ++db)
        #pragma unroll
        for (int j = 0; j < 4; ++j) {
            int srow = rowQ + lg * 4 + j;
            int dd = db * 16 + l15;
            __builtin_nontemporal_store(cacc[db][j],
                ctx + ((size_t)srow * B_ + b) * H_ + h * 64 + dd);
        }
}

extern "C" void kernel_launch(void* const* d_in, const int* in_sizes, int n_in,
                              void* d_out, int out_size, void* d_ws, size_t ws_size,
                              hipStream_t stream) {
    const float* hidden = (const float*)d_in[0];
    const float* mask   = (const float*)d_in[1];
    const float* W      = (const float*)d_in[2];
    const float* bias   = (const float*)d_in[3];

    u16* Qb = (u16*)d_ws;
    u16* Kb = Qb + 4194304;
    u16* Vt = Kb + 4194304;

    float* out    = (float*)d_out;
    float* ctx    = out;
    float* scores = out + 4194304;
    float* probs  = out + 138412032;

    u16* Ab = (u16*)scores;            // bf16 temps in not-yet-written scores region
    u16* Wb = Ab + 4194304;

    cast_bf16<<<dim3(3584), 256, 0, stream>>>(hidden, W, Ab, Wb);
    qkv_gemm<<<dim3(24, 32), 256, 0, stream>>>(Ab, Wb, bias, Qb, Kb, Vt);
    attn<<<dim3(32, 32), 256, 0, stream>>>(Qb, Kb, Vt, mask, ctx, scores, probs);
}